// Round 13
// baseline (544.914 us; speedup 1.0000x reference)
//
#include <hip/hip_runtime.h>

// VQ: B=16, C=D=256, H=64, W=64, K=1024
#define BB 16
#define CC 256
#define HH 64
#define WW 64
#define KK 1024
#define DD 256
#define HW (HH * WW)
#define TAU 0.0625f

typedef __attribute__((ext_vector_type(8))) short bf16x8;
typedef __attribute__((ext_vector_type(16))) float f32x16;

union Frag { bf16x8 v; unsigned int u[4]; };
union U4F  { uint4 u; bf16x8 v; };
__device__ inline bf16x8 asbf(const uint4 x) { U4F c; c.u = x; return c.v; }

// trunc-split 8 floats into bf16 hi/lo fragments (x = hi + lo + O(2^-16 x), Sterbenz-exact lo)
__device__ inline void split8r(const float4 a, const float4 b, Frag& hi, Frag& lo) {
    float f[8] = {a.x, a.y, a.z, a.w, b.x, b.y, b.z, b.w};
    #pragma unroll
    for (int p = 0; p < 4; ++p) {
        const unsigned int b0 = __float_as_uint(f[2 * p]), b1 = __float_as_uint(f[2 * p + 1]);
        const unsigned int h0 = b0 & 0xFFFF0000u, h1 = b1 & 0xFFFF0000u;
        const float r0 = f[2 * p]     - __uint_as_float(h0);
        const float r1 = f[2 * p + 1] - __uint_as_float(h1);
        hi.u[p] = (h0 >> 16) | h1;
        lo.u[p] = (__float_as_uint(r0) >> 16) | (__float_as_uint(r1) & 0xFFFF0000u);
    }
}

// Prep (fused): codebook bf16 hi/lo split into MFMA-fragment-linear uint4 layout
// (r9/r12-validated) + ehalf = 0.5||e||^2. 32 threads per code row.
__global__ __launch_bounds__(256) void vq_prep_kernel(const float* __restrict__ e,
                                                      float* __restrict__ ehalf,
                                                      uint4* __restrict__ ebt4) {
    const int tid = threadIdx.x;
    const int code = blockIdx.x * 8 + (tid >> 5);
    const int sub = tid & 31;
    const int ks = sub >> 1, lq = sub & 1;
    const int ct = code >> 5, lc = code & 31;
    const float* src = e + (size_t)code * DD + ks * 16 + lq * 8;
    const float4 va = *reinterpret_cast<const float4*>(src);
    const float4 vb = *reinterpret_cast<const float4*>(src + 4);
    Frag hi, lo;
    split8r(va, vb, hi, lo);
    uint4* dst = ebt4 + (size_t)ct * 2048 + ks * 128 + lq * 32 + lc;
    dst[0]  = make_uint4(hi.u[0], hi.u[1], hi.u[2], hi.u[3]);   // term 0 (hi)
    dst[64] = make_uint4(lo.u[0], lo.u[1], lo.u[2], lo.u[3]);   // term 1 (lo)
    float s = va.x * va.x + va.y * va.y + va.z * va.z + va.w * va.w
            + vb.x * vb.x + vb.y * vb.y + vb.z * vb.z + vb.w * vb.w;
    #pragma unroll
    for (int off = 16; off; off >>= 1) s += __shfl_xor(s, off, 64);  // 32-lane group reduce
    if (sub == 0) ehalf[code] = 0.5f * s;
}

// Main: one block per (b,h) = 64 tokens x all 1024 codes.
// A pre-split bf16 in LDS (depth-2 ds_read ring). B streamed from L2 through an
// EXPLICIT depth-4 register ring (16 uint4 in flight) -> counted-vmcnt pipeline.
// Margin < TAU tokens rescued INLINE with exact fp32 before the epilogue.
__global__ __launch_bounds__(256, 2) void vq_mfma_kernel(
    const float* __restrict__ in, const float* __restrict__ emb,
    const float* __restrict__ ehalf, const uint4* __restrict__ ebt4,
    float* __restrict__ out) {

    __shared__ uint4 a4[32][64][2];       // 64 KB: [ks*2+term][token][half]
    __shared__ float eh_lds[KK];
    __shared__ float mv[64][2], m2l[64][2];
    __shared__ int   mi[64][2];
    __shared__ int   idx_lds[64];
    __shared__ float xs[DD];
    __shared__ int   flags[64];
    __shared__ int   nflag;
    __shared__ float rv[4];
    __shared__ int   ri[4];

    const int tid = threadIdx.x;
    const int bid = blockIdx.x;
    const int b = bid >> 6, h = bid & 63;
    const int w = tid & 63, cs = tid >> 6;

    if (tid == 0) nflag = 0;

    // ---- stage A: load x (coalesced over w), split, write bf16 hi/lo to LDS ----
    {
        const float* src = in + (size_t)b * CC * HW + (size_t)h * WW + w;
        #pragma unroll
        for (int i = 0; i < 4; ++i) {
            const int ks = cs * 4 + i;
            float f[16];
            #pragma unroll
            for (int e = 0; e < 16; ++e) f[e] = src[(size_t)(ks * 16 + e) * HW];
            Frag h0, l0, h1, l1;
            split8r(make_float4(f[0], f[1], f[2], f[3]),
                    make_float4(f[4], f[5], f[6], f[7]), h0, l0);
            split8r(make_float4(f[8], f[9], f[10], f[11]),
                    make_float4(f[12], f[13], f[14], f[15]), h1, l1);
            a4[ks * 2][w][0]     = make_uint4(h0.u[0], h0.u[1], h0.u[2], h0.u[3]);
            a4[ks * 2][w][1]     = make_uint4(h1.u[0], h1.u[1], h1.u[2], h1.u[3]);
            a4[ks * 2 + 1][w][0] = make_uint4(l0.u[0], l0.u[1], l0.u[2], l0.u[3]);
            a4[ks * 2 + 1][w][1] = make_uint4(l1.u[0], l1.u[1], l1.u[2], l1.u[3]);
        }
        for (int k = tid; k < KK; k += 256) eh_lds[k] = ehalf[k];
    }
    __syncthreads();

    const int lane = tid & 63;
    const int wv = tid >> 6;                 // 4 waves: (mg, ng)
    const int mg = wv >> 1, ng = wv & 1;
    const int lc = lane & 31, lq = lane >> 5;
    const int trow = mg * 32 + lc;

    float bestv[16], best2[16]; int besti[16];
    #pragma unroll
    for (int r = 0; r < 16; ++r) { bestv[r] = -3.4e38f; best2[r] = -3.4e38f; besti[r] = 0; }

    // ---- K-loop: 8 passes x 2 code-tiles; explicit depth-4 B ring, depth-2 A ring ----
    #pragma unroll 1
    for (int ctj = 0; ctj < 8; ++ctj) {
        const int ct0 = ng * 16 + ctj * 2;
        const uint4* bp0 = ebt4 + (size_t)ct0 * 2048 + lane;
        const uint4* bp1 = bp0 + 2048;
        const int code0 = ct0 * 32 + lc;
        const int code1 = code0 + 32;
        const float nh0 = -eh_lds[code0];
        const float nh1 = -eh_lds[code1];
        f32x16 ah0, al0, ah1, al1;
        #pragma unroll
        for (int r = 0; r < 16; ++r) { ah0[r] = nh0; al0[r] = 0.0f; ah1[r] = nh1; al1[r] = 0.0f; }

        uint4 rb[4][4];                         // B ring: [ks&3][bh0,bl0,bh1,bl1]
        #pragma unroll
        for (int k = 0; k < 4; ++k) {
            rb[k][0] = bp0[k * 128];
            rb[k][1] = bp0[k * 128 + 64];
            rb[k][2] = bp1[k * 128];
            rb[k][3] = bp1[k * 128 + 64];
        }
        bf16x8 ra_h[2], ra_l[2];                // A ring depth 2
        ra_h[0] = asbf(a4[0][trow][lq]);
        ra_l[0] = asbf(a4[1][trow][lq]);

        #pragma unroll
        for (int ks = 0; ks < 16; ++ks) {
            const int cur = ks & 3;
            const int ca = ks & 1;
            if (ks < 15) {
                ra_h[ca ^ 1] = asbf(a4[(ks + 1) * 2][trow][lq]);
                ra_l[ca ^ 1] = asbf(a4[(ks + 1) * 2 + 1][trow][lq]);
            }
            const bf16x8 bh0 = asbf(rb[cur][0]);
            const bf16x8 bl0 = asbf(rb[cur][1]);
            const bf16x8 bh1 = asbf(rb[cur][2]);
            const bf16x8 bl1 = asbf(rb[cur][3]);
            if (ks < 12) {                      // re-issue ring slot for ks+4 (stays in flight)
                rb[cur][0] = bp0[(ks + 4) * 128];
                rb[cur][1] = bp0[(ks + 4) * 128 + 64];
                rb[cur][2] = bp1[(ks + 4) * 128];
                rb[cur][3] = bp1[(ks + 4) * 128 + 64];
            }
            const bf16x8 afh = ra_h[ca];
            const bf16x8 afl = ra_l[ca];
            ah0 = __builtin_amdgcn_mfma_f32_32x32x16_bf16(afh, bh0, ah0, 0, 0, 0);
            ah1 = __builtin_amdgcn_mfma_f32_32x32x16_bf16(afh, bh1, ah1, 0, 0, 0);
            al0 = __builtin_amdgcn_mfma_f32_32x32x16_bf16(afl, bh0, al0, 0, 0, 0);
            al1 = __builtin_amdgcn_mfma_f32_32x32x16_bf16(afl, bh1, al1, 0, 0, 0);
            ah0 = __builtin_amdgcn_mfma_f32_32x32x16_bf16(afh, bl0, ah0, 0, 0, 0);
            ah1 = __builtin_amdgcn_mfma_f32_32x32x16_bf16(afh, bl1, ah1, 0, 0, 0);
        }
        #pragma unroll
        for (int r = 0; r < 16; ++r) {
            const float v0 = ah0[r] + al0[r];
            if (v0 > bestv[r]) { best2[r] = bestv[r]; bestv[r] = v0; besti[r] = code0; }
            else if (v0 > best2[r]) best2[r] = v0;
            const float v1 = ah1[r] + al1[r];
            if (v1 > bestv[r]) { best2[r] = bestv[r]; bestv[r] = v1; besti[r] = code1; }
            else if (v1 > best2[r]) best2[r] = v1;
        }
    }

    // ---- butterfly across the 32 code-columns ----
    #pragma unroll
    for (int m = 1; m < 32; m <<= 1) {
        #pragma unroll
        for (int r = 0; r < 16; ++r) {
            const float ob = __shfl_xor(bestv[r], m, 64);
            const float o2 = __shfl_xor(best2[r], m, 64);
            const int   oi = __shfl_xor(besti[r], m, 64);
            if (ob > bestv[r] || (ob == bestv[r] && oi < besti[r])) {
                best2[r] = fmaxf(bestv[r], o2); bestv[r] = ob; besti[r] = oi;
            } else {
                best2[r] = fmaxf(best2[r], ob);
            }
        }
    }
    if (lc == 0) {
        #pragma unroll
        for (int r = 0; r < 16; ++r) {
            const int row = mg * 32 + (r & 3) + 8 * (r >> 2) + 4 * lq;  // C/D row map (m74/m101)
            mv[row][ng] = bestv[r]; m2l[row][ng] = best2[r]; mi[row][ng] = besti[r];
        }
    }
    __syncthreads();

    // ---- merge ng halves; flag small margins (block-local) ----
    if (tid < 64) {
        const float v0 = mv[tid][0], s0 = m2l[tid][0]; const int i0 = mi[tid][0];
        const float v1 = mv[tid][1], s1 = m2l[tid][1]; const int i1 = mi[tid][1];
        float fb, f2; int fi;
        if (v1 > v0 || (v1 == v0 && i1 < i0)) { fb = v1; fi = i1; f2 = fmaxf(v0, s1); }
        else { fb = v0; fi = i0; f2 = fmaxf(s0, v1); }
        idx_lds[tid] = fi;
        if (fb - f2 < TAU) { const int p = atomicAdd(&nflag, 1); flags[p] = tid; }
    }
    __syncthreads();

    // ---- inline rescue: exact fp32 recompute for flagged tokens (~0.6/block avg) ----
    const int nf = nflag;
    for (int f = 0; f < nf; ++f) {
        const int w2 = flags[f];
        xs[tid] = in[(size_t)(b * CC + tid) * HW + (size_t)h * WW + w2];
        __syncthreads();
        float best = -3.4e38f; int bidx = 0;
        #pragma unroll
        for (int cc = 0; cc < 4; ++cc) {
            const int code = tid * 4 + cc;              // ascending per thread
            float sc = -eh_lds[code];
            const float* er = emb + (size_t)code * DD;
            for (int d = 0; d < DD; d += 4) {
                sc = fmaf(xs[d + 0], er[d + 0], sc);
                sc = fmaf(xs[d + 1], er[d + 1], sc);
                sc = fmaf(xs[d + 2], er[d + 2], sc);
                sc = fmaf(xs[d + 3], er[d + 3], sc);
            }
            if (sc > best) { best = sc; bidx = code; }
        }
        #pragma unroll
        for (int m2 = 1; m2 < 64; m2 <<= 1) {
            const float ov = __shfl_xor(best, m2, 64);
            const int   oi = __shfl_xor(bidx, m2, 64);
            if (ov > best || (ov == best && oi < bidx)) { best = ov; bidx = oi; }
        }
        if ((tid & 63) == 0) { rv[tid >> 6] = best; ri[tid >> 6] = bidx; }
        __syncthreads();
        if (tid == 0) {
            float fbv = rv[0]; int fbi = ri[0];
            #pragma unroll
            for (int q = 1; q < 4; ++q)
                if (rv[q] > fbv || (rv[q] == fbv && ri[q] < fbi)) { fbv = rv[q]; fbi = ri[q]; }
            idx_lds[w2] = fbi;
        }
        __syncthreads();
    }

    // ---- epilogue: out = x + (q - x), x re-read from global (coalesced) ----
    {
        const float* srcx = in + (size_t)b * CC * HW + (size_t)h * WW + w;
        float* dst = out + (size_t)b * CC * HW + (size_t)h * WW + w;
        const float* erow = emb + (size_t)idx_lds[w] * DD;
        #pragma unroll
        for (int c = cs; c < CC; c += 4) {
            const float x = srcx[(size_t)c * HW];
            const float q = erow[c];
            dst[(size_t)c * HW] = x + (q - x);
        }
    }
}

// ---- fallback path (validated fp32 VALU kernel) if ws is too small ----
__global__ __launch_bounds__(256) void vq_enorm_kernel(const float* __restrict__ e,
                                                       float* __restrict__ ehalf) {
    const int wave = threadIdx.x >> 6;
    const int lane = threadIdx.x & 63;
    const int k = blockIdx.x * 4 + wave;
    const float4 v = *reinterpret_cast<const float4*>(e + (size_t)k * DD + lane * 4);
    float s = v.x * v.x + v.y * v.y + v.z * v.z + v.w * v.w;
    #pragma unroll
    for (int off = 32; off; off >>= 1) s += __shfl_xor(s, off, 64);
    if (lane == 0) ehalf[k] = 0.5f * s;
}

__global__ __launch_bounds__(256) void vq_fallback_kernel(
    const float* __restrict__ in, const float* __restrict__ emb,
    const float* __restrict__ ehalf, float* __restrict__ out) {

    __shared__ float x_lds[64][260];
    __shared__ float red_v[64][16];
    __shared__ int   red_i[64][16];
    __shared__ int   idx_lds[64];

    const int tid = threadIdx.x;
    const int bid = blockIdx.x;
    const int b = bid >> 6, h = bid & 63;
    const int w = tid & 63, cs = tid >> 6;
    {
        const float* src = in + (size_t)b * CC * HW + (size_t)h * WW + w;
        #pragma unroll
        for (int c = cs; c < CC; c += 4) x_lds[w][c] = src[(size_t)c * HW];
    }
    __syncthreads();
    const int i = tid & 15;
    const int j = tid >> 4;
    float best_v[4]; int best_i[4];
    #pragma unroll
    for (int t = 0; t < 4; ++t) { best_v[t] = -3.4e38f; best_i[t] = 0; }
    for (int chunk = 0; chunk < KK; chunk += 128) {
        const int c0 = chunk + j * 8;
        const float* e0 = emb + (size_t)c0 * DD;
        float acc[4][8];
        #pragma unroll
        for (int cj = 0; cj < 8; ++cj) {
            const float nh = -ehalf[c0 + cj];
            #pragma unroll
            for (int t = 0; t < 4; ++t) acc[t][cj] = nh;
        }
        #pragma unroll 2
        for (int d = 0; d < DD; d += 4) {
            float4 xv[4], ev[8];
            #pragma unroll
            for (int t = 0; t < 4; ++t)
                xv[t] = *reinterpret_cast<const float4*>(&x_lds[i + 16 * t][d]);
            #pragma unroll
            for (int cj = 0; cj < 8; ++cj)
                ev[cj] = *reinterpret_cast<const float4*>(e0 + (size_t)cj * DD + d);
            #pragma unroll
            for (int t = 0; t < 4; ++t) {
                #pragma unroll
                for (int cj = 0; cj < 8; ++cj) {
                    float a = acc[t][cj];
                    a = fmaf(xv[t].x, ev[cj].x, a);
                    a = fmaf(xv[t].y, ev[cj].y, a);
                    a = fmaf(xv[t].z, ev[cj].z, a);
                    a = fmaf(xv[t].w, ev[cj].w, a);
                    acc[t][cj] = a;
                }
            }
        }
        #pragma unroll
        for (int cj = 0; cj < 8; ++cj)
            #pragma unroll
            for (int t = 0; t < 4; ++t)
                if (acc[t][cj] > best_v[t]) { best_v[t] = acc[t][cj]; best_i[t] = c0 + cj; }
    }
    #pragma unroll
    for (int t = 0; t < 4; ++t) { red_v[i + 16 * t][j] = best_v[t]; red_i[i + 16 * t][j] = best_i[t]; }
    __syncthreads();
    if (tid < 64) {
        float bv = red_v[tid][0]; int bi = red_i[tid][0];
        #pragma unroll
        for (int jj = 1; jj < 16; ++jj) {
            const float v = red_v[tid][jj]; const int id = red_i[tid][jj];
            if (v > bv || (v == bv && id < bi)) { bv = v; bi = id; }
        }
        idx_lds[tid] = bi;
    }
    __syncthreads();
    {
        float* dst = out + (size_t)b * CC * HW + (size_t)h * WW + w;
        const float* erow = emb + (size_t)idx_lds[w] * DD;
        #pragma unroll
        for (int c = cs; c < CC; c += 4) {
            const float x = x_lds[w][c];
            const float q = erow[c];
            dst[(size_t)c * HW] = x + (q - x);
        }
    }
}

extern "C" void kernel_launch(void* const* d_in, const int* in_sizes, int n_in,
                              void* d_out, int out_size, void* d_ws, size_t ws_size,
                              hipStream_t stream) {
    const float* in  = (const float*)d_in[0];
    const float* emb = (const float*)d_in[1];
    float* out = (float*)d_out;
    char* ws = (char*)d_ws;

    float* ehalf = (float*)ws;                                 // 4 KiB
    const size_t OFF_EBT = 4096;
    const size_t NEED = OFF_EBT + (size_t)KK * DD * 2 * 2;     // + 1 MiB

    if (ws_size < NEED) {
        vq_enorm_kernel<<<KK / 4, 256, 0, stream>>>(emb, ehalf);
        vq_fallback_kernel<<<BB * HH, 256, 0, stream>>>(in, emb, ehalf, out);
        return;
    }
    uint4* ebt4 = (uint4*)(ws + OFF_EBT);

    vq_prep_kernel<<<KK / 8, 256, 0, stream>>>(emb, ehalf, ebt4);
    vq_mfma_kernel<<<BB * HH, 256, 0, stream>>>(in, emb, ehalf, ebt4, out);
}

// Round 16
// 479.796 us; speedup vs baseline: 1.1357x; 1.1357x over previous
//
#include <hip/hip_runtime.h>

// VQ: B=16, C=D=256, H=64, W=64, K=1024
#define BB 16
#define CC 256
#define HH 64
#define WW 64
#define KK 1024
#define DD 256
#define HW (HH * WW)
#define TAU 0.0625f

typedef __attribute__((ext_vector_type(8))) short bf16x8;
typedef __attribute__((ext_vector_type(4))) float f32x4;

union Frag { bf16x8 v; unsigned int u[4]; };
union U4F  { uint4 u; bf16x8 v; };
__device__ inline bf16x8 asbf(const uint4 x) { U4F c; c.u = x; return c.v; }

// trunc-split 8 floats into bf16 hi/lo fragments (x = hi + lo + O(2^-16 x), Sterbenz-exact lo)
__device__ inline void split8r(const float4 a, const float4 b, Frag& hi, Frag& lo) {
    float f[8] = {a.x, a.y, a.z, a.w, b.x, b.y, b.z, b.w};
    #pragma unroll
    for (int p = 0; p < 4; ++p) {
        const unsigned int b0 = __float_as_uint(f[2 * p]), b1 = __float_as_uint(f[2 * p + 1]);
        const unsigned int h0 = b0 & 0xFFFF0000u, h1 = b1 & 0xFFFF0000u;
        const float r0 = f[2 * p]     - __uint_as_float(h0);
        const float r1 = f[2 * p + 1] - __uint_as_float(h1);
        hi.u[p] = (h0 >> 16) | h1;
        lo.u[p] = (__float_as_uint(r0) >> 16) | (__float_as_uint(r1) & 0xFFFF0000u);
    }
}

// Prep: codebook -> bf16 hi/lo in 16x16x32-fragment-linear uint4 layout + ehalf.
// ebt4[ct*1024 + ks*128 + term*64 + lane], lane = kq*16 + col:
//   code = ct*16 + col, k-dims = ks*32 + kq*8 .. +7.  (B frag: col=lane&15, k=(lane>>4)*8)
// Thread = one (code, ks): 8192 threads, grid 32.
__global__ __launch_bounds__(256) void vq_prep_kernel(const float* __restrict__ e,
                                                      float* __restrict__ ehalf,
                                                      uint4* __restrict__ ebt4) {
    const int gt = blockIdx.x * 256 + threadIdx.x;
    const int code = gt >> 3, ks = gt & 7;
    const int ct = code >> 4, col = code & 15;
    const float* src = e + (size_t)code * DD + ks * 32;
    float s = 0.0f;
    #pragma unroll
    for (int kq = 0; kq < 4; ++kq) {
        const float4 va = *reinterpret_cast<const float4*>(src + kq * 8);
        const float4 vb = *reinterpret_cast<const float4*>(src + kq * 8 + 4);
        Frag hi, lo;
        split8r(va, vb, hi, lo);
        const size_t base = (size_t)ct * 1024 + ks * 128 + kq * 16 + col;
        ebt4[base]      = make_uint4(hi.u[0], hi.u[1], hi.u[2], hi.u[3]);  // term 0
        ebt4[base + 64] = make_uint4(lo.u[0], lo.u[1], lo.u[2], lo.u[3]);  // term 1
        s += va.x * va.x + va.y * va.y + va.z * va.z + va.w * va.w
           + vb.x * vb.x + vb.y * vb.y + vb.z * vb.z + vb.w * vb.w;
    }
    #pragma unroll
    for (int off = 1; off < 8; off <<= 1) s += __shfl_xor(s, off, 64);  // 8 ks-threads/code
    if (ks == 0) ehalf[code] = 0.5f * s;
}

// Main: one block per (b,h) = 64 tokens; wave mg -> tokens mg*16..+15, ALL 1024 codes.
// A: 16 bf16x8 hi/lo frag-pairs fully in registers (64 VGPR).
// Acc: per 4-ct pass, 8 independent f32x4 chains (32 VGPR) -> no spill, deep MFMA ILP.
// B: fragment-linear stream from L2/L1 (4 waves sweep same order -> L1 reuse).
// No LDS / barriers in K-loop. Inline exact-fp32 rescue for margin < TAU.
__global__ __launch_bounds__(256) void vq_mfma_kernel(
    const float* __restrict__ in, const float* __restrict__ emb,
    const float* __restrict__ ehalf, const uint4* __restrict__ ebt4,
    float* __restrict__ out) {

    __shared__ float eh_lds[KK];
    __shared__ int   idx_lds[64];
    __shared__ float xs[DD];
    __shared__ int   flags[64];
    __shared__ int   nflag;
    __shared__ float rv[4];
    __shared__ int   ri[4];

    const int tid = threadIdx.x;
    const int bid = blockIdx.x;
    const int b = bid >> 6, h = bid & 63;

    if (tid == 0) nflag = 0;
    for (int k = tid; k < KK; k += 256) eh_lds[k] = ehalf[k];

    const int lane = tid & 63;
    const int mg = tid >> 6;            // 4 waves x 16 tokens
    const int lr = lane & 15, lq = lane >> 4;
    const int w2 = mg * 16 + lr;        // A row token for this lane

    // ---- A fragments: 8 k-steps x (hi,lo), 64 VGPRs, loaded once ----
    bf16x8 ah[8], al[8];
    {
        const float* asrc = in + (size_t)b * CC * HW + (size_t)h * WW + w2;
        #pragma unroll
        for (int ks = 0; ks < 8; ++ks) {
            const int c0 = ks * 32 + lq * 8;
            float f[8];
            #pragma unroll
            for (int di = 0; di < 8; ++di) f[di] = asrc[(size_t)(c0 + di) * HW];
            Frag hi, lo;
            split8r(make_float4(f[0], f[1], f[2], f[3]),
                    make_float4(f[4], f[5], f[6], f[7]), hi, lo);
            ah[ks] = hi.v; al[ks] = lo.v;
        }
    }
    __syncthreads();   // eh_lds ready

    float bestv[4], best2[4]; int besti[4];
    #pragma unroll
    for (int r = 0; r < 4; ++r) { bestv[r] = -3.4e38f; best2[r] = -3.4e38f; besti[r] = 0; }

    // ---- K-loop: 16 passes x 4 code-tiles (64 codes/pass) ----
    #pragma unroll 1
    for (int pass = 0; pass < 16; ++pass) {
        const uint4* bp = ebt4 + (size_t)pass * 4096 + lane;
        f32x4 acch[4], accl[4];
        #pragma unroll
        for (int j = 0; j < 4; ++j) {
            const float nh = -eh_lds[(pass * 4 + j) * 16 + lr];
            acch[j] = (f32x4){nh, nh, nh, nh};
            accl[j] = (f32x4){0.0f, 0.0f, 0.0f, 0.0f};
        }
        #pragma unroll
        for (int ks = 0; ks < 8; ++ks) {
            uint4 bhu[4], blu[4];
            #pragma unroll
            for (int j = 0; j < 4; ++j) {
                bhu[j] = bp[j * 1024 + ks * 128];
                blu[j] = bp[j * 1024 + ks * 128 + 64];
            }
            #pragma unroll
            for (int j = 0; j < 4; ++j)
                acch[j] = __builtin_amdgcn_mfma_f32_16x16x32_bf16(ah[ks], asbf(bhu[j]), acch[j], 0, 0, 0);
            #pragma unroll
            for (int j = 0; j < 4; ++j)
                accl[j] = __builtin_amdgcn_mfma_f32_16x16x32_bf16(al[ks], asbf(bhu[j]), accl[j], 0, 0, 0);
            #pragma unroll
            for (int j = 0; j < 4; ++j)
                acch[j] = __builtin_amdgcn_mfma_f32_16x16x32_bf16(ah[ks], asbf(blu[j]), acch[j], 0, 0, 0);
        }
        #pragma unroll
        for (int j = 0; j < 4; ++j) {
            const int code = (pass * 4 + j) * 16 + lr;     // ascending per lane
            #pragma unroll
            for (int r = 0; r < 4; ++r) {
                const float v = acch[j][r] + accl[j][r];
                if (v > bestv[r]) { best2[r] = bestv[r]; bestv[r] = v; besti[r] = code; }
                else if (v > best2[r]) best2[r] = v;
            }
        }
    }

    // ---- butterfly across the 16 code-columns (low 4 lane bits) ----
    #pragma unroll
    for (int m = 1; m < 16; m <<= 1) {
        #pragma unroll
        for (int r = 0; r < 4; ++r) {
            const float ob = __shfl_xor(bestv[r], m, 64);
            const float o2 = __shfl_xor(best2[r], m, 64);
            const int   oi = __shfl_xor(besti[r], m, 64);
            if (ob > bestv[r] || (ob == bestv[r] && oi < besti[r])) {
                best2[r] = fmaxf(bestv[r], o2); bestv[r] = ob; besti[r] = oi;
            } else {
                best2[r] = fmaxf(best2[r], ob);
            }
        }
    }
    if (lr == 0) {
        #pragma unroll
        for (int r = 0; r < 4; ++r) {
            const int tok = mg * 16 + lq * 4 + r;          // C/D row = lq*4 + r (r6-validated)
            idx_lds[tok] = besti[r];
            if (bestv[r] - best2[r] < TAU) { const int p = atomicAdd(&nflag, 1); flags[p] = tok; }
        }
    }
    __syncthreads();

    // ---- inline rescue: exact fp32 recompute for flagged tokens (r13-validated) ----
    const int nf = nflag;
    for (int f = 0; f < nf; ++f) {
        const int wf = flags[f];
        xs[tid] = in[(size_t)(b * CC + tid) * HW + (size_t)h * WW + wf];
        __syncthreads();
        float best = -3.4e38f; int bidx = 0;
        #pragma unroll
        for (int cc = 0; cc < 4; ++cc) {
            const int code = tid * 4 + cc;                 // ascending per thread
            float sc = -eh_lds[code];
            const float* er = emb + (size_t)code * DD;
            for (int d = 0; d < DD; d += 4) {
                sc = fmaf(xs[d + 0], er[d + 0], sc);
                sc = fmaf(xs[d + 1], er[d + 1], sc);
                sc = fmaf(xs[d + 2], er[d + 2], sc);
                sc = fmaf(xs[d + 3], er[d + 3], sc);
            }
            if (sc > best) { best = sc; bidx = code; }
        }
        #pragma unroll
        for (int m2 = 1; m2 < 64; m2 <<= 1) {
            const float ov = __shfl_xor(best, m2, 64);
            const int   oi = __shfl_xor(bidx, m2, 64);
            if (ov > best || (ov == best && oi < bidx)) { best = ov; bidx = oi; }
        }
        if ((tid & 63) == 0) { rv[tid >> 6] = best; ri[tid >> 6] = bidx; }
        __syncthreads();
        if (tid == 0) {
            float fbv = rv[0]; int fbi = ri[0];
            #pragma unroll
            for (int q = 1; q < 4; ++q)
                if (rv[q] > fbv || (rv[q] == fbv && ri[q] < fbi)) { fbv = rv[q]; fbi = ri[q]; }
            idx_lds[wf] = fbi;
        }
        __syncthreads();
    }

    // ---- epilogue: out = x + (q - x), coalesced over w (r12-validated) ----
    {
        const int w = tid & 63, cs = tid >> 6;
        const float* srcx = in + (size_t)b * CC * HW + (size_t)h * WW + w;
        float* dst = out + (size_t)b * CC * HW + (size_t)h * WW + w;
        const float* erow = emb + (size_t)idx_lds[w] * DD;
        #pragma unroll
        for (int c = cs; c < CC; c += 4) {
            const float x = srcx[(size_t)c * HW];
            const float q = erow[c];
            dst[(size_t)c * HW] = x + (q - x);
        }
    }
}

// ---- fallback path (validated fp32 VALU kernel) if ws is too small ----
__global__ __launch_bounds__(256) void vq_enorm_kernel(const float* __restrict__ e,
                                                       float* __restrict__ ehalf) {
    const int wave = threadIdx.x >> 6;
    const int lane = threadIdx.x & 63;
    const int k = blockIdx.x * 4 + wave;
    const float4 v = *reinterpret_cast<const float4*>(e + (size_t)k * DD + lane * 4);
    float s = v.x * v.x + v.y * v.y + v.z * v.z + v.w * v.w;
    #pragma unroll
    for (int off = 32; off; off >>= 1) s += __shfl_xor(s, off, 64);
    if (lane == 0) ehalf[k] = 0.5f * s;
}

__global__ __launch_bounds__(256) void vq_fallback_kernel(
    const float* __restrict__ in, const float* __restrict__ emb,
    const float* __restrict__ ehalf, float* __restrict__ out) {

    __shared__ float x_lds[64][260];
    __shared__ float red_v[64][16];
    __shared__ int   red_i[64][16];
    __shared__ int   idx_lds[64];

    const int tid = threadIdx.x;
    const int bid = blockIdx.x;
    const int b = bid >> 6, h = bid & 63;
    const int w = tid & 63, cs = tid >> 6;
    {
        const float* src = in + (size_t)b * CC * HW + (size_t)h * WW + w;
        #pragma unroll
        for (int c = cs; c < CC; c += 4) x_lds[w][c] = src[(size_t)c * HW];
    }
    __syncthreads();
    const int i = tid & 15;
    const int j = tid >> 4;
    float best_v[4]; int best_i[4];
    #pragma unroll
    for (int t = 0; t < 4; ++t) { best_v[t] = -3.4e38f; best_i[t] = 0; }
    for (int chunk = 0; chunk < KK; chunk += 128) {
        const int c0 = chunk + j * 8;
        const float* e0 = emb + (size_t)c0 * DD;
        float acc[4][8];
        #pragma unroll
        for (int cj = 0; cj < 8; ++cj) {
            const float nh = -ehalf[c0 + cj];
            #pragma unroll
            for (int t = 0; t < 4; ++t) acc[t][cj] = nh;
        }
        #pragma unroll 2
        for (int d = 0; d < DD; d += 4) {
            float4 xv[4], ev[8];
            #pragma unroll
            for (int t = 0; t < 4; ++t)
                xv[t] = *reinterpret_cast<const float4*>(&x_lds[i + 16 * t][d]);
            #pragma unroll
            for (int cj = 0; cj < 8; ++cj)
                ev[cj] = *reinterpret_cast<const float4*>(e0 + (size_t)cj * DD + d);
            #pragma unroll
            for (int t = 0; t < 4; ++t) {
                #pragma unroll
                for (int cj = 0; cj < 8; ++cj) {
                    float a = acc[t][cj];
                    a = fmaf(xv[t].x, ev[cj].x, a);
                    a = fmaf(xv[t].y, ev[cj].y, a);
                    a = fmaf(xv[t].z, ev[cj].z, a);
                    a = fmaf(xv[t].w, ev[cj].w, a);
                    acc[t][cj] = a;
                }
            }
        }
        #pragma unroll
        for (int cj = 0; cj < 8; ++cj)
            #pragma unroll
            for (int t = 0; t < 4; ++t)
                if (acc[t][cj] > best_v[t]) { best_v[t] = acc[t][cj]; best_i[t] = c0 + cj; }
    }
    #pragma unroll
    for (int t = 0; t < 4; ++t) { red_v[i + 16 * t][j] = best_v[t]; red_i[i + 16 * t][j] = best_i[t]; }
    __syncthreads();
    if (tid < 64) {
        float bv = red_v[tid][0]; int bi = red_i[tid][0];
        #pragma unroll
        for (int jj = 1; jj < 16; ++jj) {
            const float v = red_v[tid][jj]; const int id = red_i[tid][jj];
            if (v > bv || (v == bv && id < bi)) { bv = v; bi = id; }
        }
        idx_lds[tid] = bi;
    }
    __syncthreads();
    {
        float* dst = out + (size_t)b * CC * HW + (size_t)h * WW + w;
        const float* erow = emb + (size_t)idx_lds[w] * DD;
        #pragma unroll
        for (int c = cs; c < CC; c += 4) {
            const float x = x_lds[w][c];
            const float q = erow[c];
            dst[(size_t)c * HW] = x + (q - x);
        }
    }
}

extern "C" void kernel_launch(void* const* d_in, const int* in_sizes, int n_in,
                              void* d_out, int out_size, void* d_ws, size_t ws_size,
                              hipStream_t stream) {
    const float* in  = (const float*)d_in[0];
    const float* emb = (const float*)d_in[1];
    float* out = (float*)d_out;
    char* ws = (char*)d_ws;

    float* ehalf = (float*)ws;                                 // 4 KiB
    const size_t OFF_EBT = 4096;
    const size_t NEED = OFF_EBT + (size_t)KK * DD * 2 * 2;     // + 1 MiB

    if (ws_size < NEED) {
        vq_enorm_kernel<<<KK / 4, 256, 0, stream>>>(emb, ehalf);
        vq_fallback_kernel<<<BB * HH, 256, 0, stream>>>(in, emb, ehalf, out);
        return;
    }
    uint4* ebt4 = (uint4*)(ws + OFF_EBT);

    vq_prep_kernel<<<32, 256, 0, stream>>>(emb, ehalf, ebt4);
    vq_mfma_kernel<<<BB * HH, 256, 0, stream>>>(in, emb, ehalf, ebt4, out);
}